// Round 5
// baseline (186.022 us; speedup 1.0000x reference)
//
#include <hip/hip_runtime.h>

#define P_TOTAL 8192
#define F_TOTAL 2048
#define TPB     256                      // 4 waves; wave w owns point base+w
#define CHUNK   256                      // tris staged per LDS pass (12 KB SoA)
#define NCHUNK  (F_TOTAL / CHUNK)        // 8
#define SUBS    (CHUNK / 64)             // 4 tris per lane per chunk

// Wave-per-point exact scan. Lane l of wave w evaluates tris {s*64+l} of each
// chunk for point (blockIdx.x*4 + w). Bit-exact-vs-numpy arithmetic (contract
// off, numpy op order, region-first + IEEE divisions with reference-identical
// operands; shared denominator D is bit-safe: vertex regions divide by 1.0,
// and 0/G == +0 matches the reference's 0). Packed (bits<<32|idx) shuffle-min
// reproduces argmin first-match semantics.
// LDS is SoA float4 arrays: lane l reads t0[s*64+l] -> consecutive lanes read
// consecutive 16B -> conflict-free ds_read_b128 (R4's AoS 48B stride was
// 8-way conflicted: 3.1M SQ_LDS_BANK_CONFLICT).
// Loss fused: one atomicAdd per wave (out[0] zeroed by a 4B memset node).
__global__ __launch_bounds__(TPB) void msdf_main(
    const float* __restrict__ verts, const int* __restrict__ faces,
    const float* __restrict__ points, float* __restrict__ out)
{
    __shared__ float4 t0[CHUNK], t1[CHUNK], t2[CHUNK];   // 12 KB total
    const int tid  = threadIdx.x;
    const int lane = tid & 63;
    const int w    = tid >> 6;
    const int p    = blockIdx.x * 4 + w;          // wave-uniform point id

    const float px = points[3 * p], py = points[3 * p + 1], pz = points[3 * p + 2];

    unsigned int best_bits = 0xFFFFFFFFu;
    int best_idx = 0;

    for (int c = 0; c < NCHUNK; ++c) {
        __syncthreads();                 // protect LDS buffer reuse
        {   // stage: thread tid gathers tri c*256+tid (1:1, contiguous writes)
            int tg = c * CHUNK + tid;
            int i0 = faces[3 * tg + 0], i1 = faces[3 * tg + 1], i2 = faces[3 * tg + 2];
            float ax = verts[3 * i0], ay = verts[3 * i0 + 1], az = verts[3 * i0 + 2];
            float bx = verts[3 * i1], by = verts[3 * i1 + 1], bz = verts[3 * i1 + 2];
            float cx = verts[3 * i2], cy = verts[3 * i2 + 1], cz = verts[3 * i2 + 2];
            t0[tid] = make_float4(ax, ay, az, bx);
            t1[tid] = make_float4(by, bz, cx, cy);
            t2[tid] = make_float4(cz, 0.f, 0.f, 0.f);
        }
        __syncthreads();

        #pragma unroll
        for (int s = 0; s < SUBS; ++s) {
            #pragma clang fp contract(off)
            int tl = s * 64 + lane;
            float4 q0 = t0[tl];
            float4 q1 = t1[tl];
            float4 q2 = t2[tl];
            float ax = q0.x, ay = q0.y, az = q0.z;
            float bx = q0.w, by = q1.x, bz = q1.y;
            float cx = q1.z, cy = q1.w, cz = q2.x;

            float abx = bx - ax, aby = by - ay, abz = bz - az;
            float acx = cx - ax, acy = cy - ay, acz = cz - az;
            float apx = px - ax, apy = py - ay, apz = pz - az;
            float d1 = (abx * apx + aby * apy) + abz * apz;
            float d2 = (acx * apx + acy * apy) + acz * apz;
            float bpx = px - bx, bpy = py - by, bpz = pz - bz;
            float d3 = (abx * bpx + aby * bpy) + abz * bpz;
            float d4 = (acx * bpx + acy * bpy) + acz * bpz;
            float cpx = px - cx, cpy = py - cy, cpz = pz - cz;
            float d5 = (abx * cpx + aby * cpy) + abz * cpz;
            float d6 = (acx * cpx + acy * cpy) + acz * cpz;

            float vc = d1 * d4 - d3 * d2;
            float vb = d5 * d2 - d1 * d6;
            float va = d3 * d6 - d5 * d4;
            float d43 = d4 - d3, d56 = d5 - d6;

            float G1 = fmaxf(d1 - d3, 1e-12f);          // t_ab denom
            float G2 = fmaxf(d2 - d6, 1e-12f);          // t_ac denom
            float G3 = fmaxf(d43 + d56, 1e-12f);        // t_bc denom
            float G4 = fmaxf((va + vb) + vc, 1e-12f);   // interior denom

            bool cA  = (d1 <= 0.f) & (d2 <= 0.f);
            bool cB  = (d3 >= 0.f) & (d4 <= d3);
            bool cAB = (vc <= 0.f) & (d1 >= 0.f) & (d3 <= 0.f);
            bool cC  = (d6 >= 0.f) & (d5 <= d6);
            bool cAC = (vb <= 0.f) & (d2 >= 0.f) & (d6 <= 0.f);
            bool cBC = (va <= 0.f) & (d43 >= 0.f) & (d56 >= 0.f);

            // first-match selects; single shared denominator D (bit-safe).
            float nv = cA ? 0.f : cB ? 1.f : cAB ? d1 : cC ? 0.f
                     : cAC ? 0.f : cBC ? d43 : vb;
            float nw = cA ? 0.f : cB ? 0.f : cAB ? 0.f : cC ? 1.f
                     : cAC ? d2 : cBC ? d43 : vc;
            float D  = cA ? 1.f : cB ? 1.f : cAB ? G1 : cC ? 1.f
                     : cAC ? G2 : cBC ? G3 : G4;
            // first-match == BC (mask-only ops)
            bool fBC = cBC && !(cA || cB || cAB || cC || cAC);

            float qv = nv / D;                    // IEEE, ref-identical operands
            float bw = nw / D;
            float bv = fBC ? (1.0f - qv) : qv;    // reference: 1.0 - t_bc
            float bu = (1.0f - bv) - bw;

            float cpx2 = (ax * bu + bx * bv) + cx * bw;
            float cpy2 = (ay * bu + by * bv) + cy * bw;
            float cpz2 = (az * bu + bz * bv) + cz * bw;
            float dx = px - cpx2, dy = py - cpy2, dz = pz - cpz2;
            float dist2 = (dx * dx + dy * dy) + dz * dz;

            unsigned int bits = __float_as_uint(dist2);   // >=0: order-preserving
            if (bits < best_bits) { best_bits = bits; best_idx = c * CHUNK + tl; }
        }
    }

    // in-wave packed min: smallest (bits, idx) == first-match argmin
    unsigned long long key =
        ((unsigned long long)best_bits << 32) | (unsigned int)best_idx;
    #pragma unroll
    for (int off = 32; off > 0; off >>= 1) {
        unsigned int hi = (unsigned int)(key >> 32);
        unsigned int lo = (unsigned int)(key & 0xFFFFFFFFu);
        unsigned int ohi = __shfl_down(hi, off, 64);
        unsigned int olo = __shfl_down(lo, off, 64);
        unsigned long long ok = ((unsigned long long)ohi << 32) | olo;
        key = (ok < key) ? ok : key;
    }
    if (lane == 0) {
        float dist = __uint_as_float((unsigned int)(key >> 32));
        out[1 + p]           = dist;
        out[1 + P_TOTAL + p] = (float)(unsigned int)(key & 0xFFFFFFFFu);
        atomicAdd(out, dist * (1000.0f / (float)P_TOTAL));
    }
}

extern "C" void kernel_launch(void* const* d_in, const int* in_sizes, int n_in,
                              void* d_out, int out_size, void* d_ws, size_t ws_size,
                              hipStream_t stream) {
    const float* verts  = (const float*)d_in[0];
    const int*   faces  = (const int*)d_in[1];
    const float* points = (const float*)d_in[2];
    float* out = (float*)d_out;

    // zero the fused-loss accumulator (harness re-poisons d_out to 0xAA)
    hipMemsetAsync(d_out, 0, sizeof(float), stream);
    msdf_main<<<dim3(P_TOTAL / 4), dim3(TPB), 0, stream>>>(verts, faces, points, out);
}

// Round 6
// 118.994 us; speedup vs baseline: 1.5633x; 1.5633x over previous
//
#include <hip/hip_runtime.h>

#define P_TOTAL 8192
#define F_TOTAL 2048
#define TPB     256                      // 4 waves; wave w owns point base+w
#define CHUNK   256                      // tris staged per LDS pass (12 KB SoA)
#define NCHUNK  (F_TOTAL / CHUNK)        // 8
#define SUBS    (CHUNK / 64)             // 4 tris per lane per chunk

// Wave-per-point exact scan. Lane l of wave w evaluates tris {s*64+l} of each
// chunk for point (blockIdx.x*4 + w). Bit-exact-vs-numpy arithmetic (contract
// off, numpy op order, region-first + IEEE divisions with reference-identical
// operands). Packed (bits<<32|idx) shuffle-min reproduces argmin first-match.
// LDS is SoA float4 (conflict-minimal ds_read_b128, R5-verified).
// NO global atomics anywhere: R5 showed 8192 same-address atomicAdds
// serialize at ~19cyc each (+66us tail, VALUBusy 79->41%). Loss is a
// deterministic single-block kernel (harness overhead ~47us dominates it).
__global__ __launch_bounds__(TPB) void msdf_main(
    const float* __restrict__ verts, const int* __restrict__ faces,
    const float* __restrict__ points, float* __restrict__ out)
{
    __shared__ float4 t0[CHUNK], t1[CHUNK], t2[CHUNK];   // 12 KB total
    const int tid  = threadIdx.x;
    const int lane = tid & 63;
    const int w    = tid >> 6;
    const int p    = blockIdx.x * 4 + w;          // wave-uniform point id

    const float px = points[3 * p], py = points[3 * p + 1], pz = points[3 * p + 2];

    unsigned int best_bits = 0xFFFFFFFFu;
    int best_idx = 0;

    for (int c = 0; c < NCHUNK; ++c) {
        __syncthreads();                 // protect LDS buffer reuse
        {   // stage: thread tid gathers tri c*256+tid (1:1, contiguous writes)
            int tg = c * CHUNK + tid;
            int i0 = faces[3 * tg + 0], i1 = faces[3 * tg + 1], i2 = faces[3 * tg + 2];
            float ax = verts[3 * i0], ay = verts[3 * i0 + 1], az = verts[3 * i0 + 2];
            float bx = verts[3 * i1], by = verts[3 * i1 + 1], bz = verts[3 * i1 + 2];
            float cx = verts[3 * i2], cy = verts[3 * i2 + 1], cz = verts[3 * i2 + 2];
            t0[tid] = make_float4(ax, ay, az, bx);
            t1[tid] = make_float4(by, bz, cx, cy);
            t2[tid] = make_float4(cz, 0.f, 0.f, 0.f);
        }
        __syncthreads();

        #pragma unroll
        for (int s = 0; s < SUBS; ++s) {
            #pragma clang fp contract(off)
            int tl = s * 64 + lane;
            float4 q0 = t0[tl];
            float4 q1 = t1[tl];
            float4 q2 = t2[tl];
            float ax = q0.x, ay = q0.y, az = q0.z;
            float bx = q0.w, by = q1.x, bz = q1.y;
            float cx = q1.z, cy = q1.w, cz = q2.x;

            float abx = bx - ax, aby = by - ay, abz = bz - az;
            float acx = cx - ax, acy = cy - ay, acz = cz - az;
            float apx = px - ax, apy = py - ay, apz = pz - az;
            float d1 = (abx * apx + aby * apy) + abz * apz;
            float d2 = (acx * apx + acy * apy) + acz * apz;
            float bpx = px - bx, bpy = py - by, bpz = pz - bz;
            float d3 = (abx * bpx + aby * bpy) + abz * bpz;
            float d4 = (acx * bpx + acy * bpy) + acz * bpz;
            float cpx = px - cx, cpy = py - cy, cpz = pz - cz;
            float d5 = (abx * cpx + aby * cpy) + abz * cpz;
            float d6 = (acx * cpx + acy * cpy) + acz * cpz;

            float vc = d1 * d4 - d3 * d2;
            float vb = d5 * d2 - d1 * d6;
            float va = d3 * d6 - d5 * d4;
            float d43 = d4 - d3, d56 = d5 - d6;

            float G1 = fmaxf(d1 - d3, 1e-12f);          // t_ab denom
            float G2 = fmaxf(d2 - d6, 1e-12f);          // t_ac denom
            float G3 = fmaxf(d43 + d56, 1e-12f);        // t_bc denom
            float G4 = fmaxf((va + vb) + vc, 1e-12f);   // interior denom

            bool cA  = (d1 <= 0.f) & (d2 <= 0.f);
            bool cB  = (d3 >= 0.f) & (d4 <= d3);
            bool cAB = (vc <= 0.f) & (d1 >= 0.f) & (d3 <= 0.f);
            bool cC  = (d6 >= 0.f) & (d5 <= d6);
            bool cAC = (vb <= 0.f) & (d2 >= 0.f) & (d6 <= 0.f);
            bool cBC = (va <= 0.f) & (d43 >= 0.f) & (d56 >= 0.f);

            // first-match selects; single shared denominator D (bit-safe:
            // vertex regions divide by 1.0, 0/G == +0 matches reference's 0).
            float nv = cA ? 0.f : cB ? 1.f : cAB ? d1 : cC ? 0.f
                     : cAC ? 0.f : cBC ? d43 : vb;
            float nw = cA ? 0.f : cB ? 0.f : cAB ? 0.f : cC ? 1.f
                     : cAC ? d2 : cBC ? d43 : vc;
            float D  = cA ? 1.f : cB ? 1.f : cAB ? G1 : cC ? 1.f
                     : cAC ? G2 : cBC ? G3 : G4;
            // first-match == BC (mask-only ops)
            bool fBC = cBC && !(cA || cB || cAB || cC || cAC);

            float qv = nv / D;                    // IEEE, ref-identical operands
            float bw = nw / D;
            float bv = fBC ? (1.0f - qv) : qv;    // reference: 1.0 - t_bc
            float bu = (1.0f - bv) - bw;

            float cpx2 = (ax * bu + bx * bv) + cx * bw;
            float cpy2 = (ay * bu + by * bv) + cy * bw;
            float cpz2 = (az * bu + bz * bv) + cz * bw;
            float dx = px - cpx2, dy = py - cpy2, dz = pz - cpz2;
            float dist2 = (dx * dx + dy * dy) + dz * dz;

            unsigned int bits = __float_as_uint(dist2);   // >=0: order-preserving
            if (bits < best_bits) { best_bits = bits; best_idx = c * CHUNK + tl; }
        }
    }

    // in-wave packed min: smallest (bits, idx) == first-match argmin
    unsigned long long key =
        ((unsigned long long)best_bits << 32) | (unsigned int)best_idx;
    #pragma unroll
    for (int off = 32; off > 0; off >>= 1) {
        unsigned int hi = (unsigned int)(key >> 32);
        unsigned int lo = (unsigned int)(key & 0xFFFFFFFFu);
        unsigned int ohi = __shfl_down(hi, off, 64);
        unsigned int olo = __shfl_down(lo, off, 64);
        unsigned long long ok = ((unsigned long long)ohi << 32) | olo;
        key = (ok < key) ? ok : key;
    }
    if (lane == 0) {
        out[1 + p]           = __uint_as_float((unsigned int)(key >> 32));
        out[1 + P_TOTAL + p] = (float)(unsigned int)(key & 0xFFFFFFFFu);
    }
}

// Deterministic single-block loss reduction: out[0] = sum(dist) * 1000/P.
// No atomics; ~free under the ~47us fixed harness overhead.
__global__ __launch_bounds__(256) void msdf_loss(float* __restrict__ out)
{
    __shared__ float wsum[4];
    float s = 0.f;
    for (int k = 0; k < P_TOTAL / 256; ++k)
        s += out[1 + k * 256 + threadIdx.x];
    #pragma unroll
    for (int off = 32; off > 0; off >>= 1) s += __shfl_down(s, off, 64);
    int lane = threadIdx.x & 63, w = threadIdx.x >> 6;
    if (lane == 0) wsum[w] = s;
    __syncthreads();
    if (threadIdx.x == 0) {
        float tot = ((wsum[0] + wsum[1]) + wsum[2]) + wsum[3];
        out[0] = tot * (1000.0f / (float)P_TOTAL);
    }
}

extern "C" void kernel_launch(void* const* d_in, const int* in_sizes, int n_in,
                              void* d_out, int out_size, void* d_ws, size_t ws_size,
                              hipStream_t stream) {
    const float* verts  = (const float*)d_in[0];
    const int*   faces  = (const int*)d_in[1];
    const float* points = (const float*)d_in[2];
    float* out = (float*)d_out;

    msdf_main<<<dim3(P_TOTAL / 4), dim3(TPB), 0, stream>>>(verts, faces, points, out);
    msdf_loss<<<dim3(1), dim3(256), 0, stream>>>(out);
}

// Round 7
// 115.238 us; speedup vs baseline: 1.6142x; 1.0326x over previous
//
#include <hip/hip_runtime.h>

typedef float v2f __attribute__((ext_vector_type(2)));

#define P_TOTAL 8192
#define F_TOTAL 2048
#define TPB     256                      // 4 waves; wave w owns point base+w
#define CHUNK   256                      // tris staged per LDS pass
#define NCHUNK  (F_TOTAL / CHUNK)        // 8

// Scalar region-select + two IEEE divisions with reference-identical operands
// (bit-exact vs numpy; logic proven in R2..R6). One element of a packed pair.
__device__ __forceinline__ void region_select(
    float d1, float d2, float d3, float d4, float d5, float d6,
    float va, float vb, float vc, float d43, float d56,
    float g1, float g2, float g3, float g4,
    float& bu, float& bv, float& bw)
{
#pragma clang fp contract(off)
    float G1 = fmaxf(g1, 1e-12f);          // t_ab denom
    float G2 = fmaxf(g2, 1e-12f);          // t_ac denom
    float G3 = fmaxf(g3, 1e-12f);          // t_bc denom
    float G4 = fmaxf(g4, 1e-12f);          // interior denom

    bool cA  = (d1 <= 0.f) & (d2 <= 0.f);
    bool cB  = (d3 >= 0.f) & (d4 <= d3);
    bool cAB = (vc <= 0.f) & (d1 >= 0.f) & (d3 <= 0.f);
    bool cC  = (d6 >= 0.f) & (d5 <= d6);
    bool cAC = (vb <= 0.f) & (d2 >= 0.f) & (d6 <= 0.f);
    bool cBC = (va <= 0.f) & (d43 >= 0.f) & (d56 >= 0.f);

    // first-match selects; shared denominator D is bit-safe (vertex regions
    // divide by 1.0; 0/G == +0 matches the reference's 0).
    float nv = cA ? 0.f : cB ? 1.f : cAB ? d1 : cC ? 0.f
             : cAC ? 0.f : cBC ? d43 : vb;
    float nw = cA ? 0.f : cB ? 0.f : cAB ? 0.f : cC ? 1.f
             : cAC ? d2 : cBC ? d43 : vc;
    float D  = cA ? 1.f : cB ? 1.f : cAB ? G1 : cC ? 1.f
             : cAC ? G2 : cBC ? G3 : G4;
    bool fBC = cBC && !(cA || cB || cAB || cC || cAC);

    float qv  = nv / D;                    // IEEE, ref-identical operands
    float bww = nw / D;
    float bvv = fBC ? (1.0f - qv) : qv;    // reference: 1.0 - t_bc
    bv = bvv; bw = bww;
    bu = (1.0f - bvv) - bww;
}

// Wave-per-point exact scan, 2 triangles/lane via packed f32 (VOP3P
// v_pk_mul/add_f32 are element-wise IEEE -> bit-exactness preserved).
// LDS component-major float[15][256]: lane l reads tris (k*128+2l, +1) as one
// aligned ds_read_b64 straight into a VGPR pair (no repack movs). Edges ab/ac
// precomputed at staging (same ops on same exact inputs -> identical bits).
// Strict '<' in even-then-odd index order preserves argmin first-match.
__global__ __launch_bounds__(TPB) void msdf_main(
    const float* __restrict__ verts, const int* __restrict__ faces,
    const float* __restrict__ points, float* __restrict__ out)
{
#pragma clang fp contract(off)
    __shared__ float sT[15][CHUNK];      // 15 KB, component-major
    const int tid  = threadIdx.x;
    const int lane = tid & 63;
    const int w    = tid >> 6;
    const int p    = blockIdx.x * 4 + w;          // wave-uniform point id

    const float px = points[3 * p], py = points[3 * p + 1], pz = points[3 * p + 2];

    unsigned int best_bits = 0xFFFFFFFFu;
    int best_idx = 0;

    for (int c = 0; c < NCHUNK; ++c) {
        __syncthreads();                 // protect LDS buffer reuse
        {   // stage: thread tid gathers tri c*256+tid; writes conflict-free
            int tg = c * CHUNK + tid;
            int i0 = faces[3 * tg + 0], i1 = faces[3 * tg + 1], i2 = faces[3 * tg + 2];
            float ax = verts[3 * i0], ay = verts[3 * i0 + 1], az = verts[3 * i0 + 2];
            float bx = verts[3 * i1], by = verts[3 * i1 + 1], bz = verts[3 * i1 + 2];
            float cx = verts[3 * i2], cy = verts[3 * i2 + 1], cz = verts[3 * i2 + 2];
            sT[0][tid] = ax;  sT[1][tid] = ay;  sT[2][tid] = az;
            sT[3][tid] = bx;  sT[4][tid] = by;  sT[5][tid] = bz;
            sT[6][tid] = cx;  sT[7][tid] = cy;  sT[8][tid] = cz;
            sT[9][tid]  = bx - ax;  sT[10][tid] = by - ay;  sT[11][tid] = bz - az;
            sT[12][tid] = cx - ax;  sT[13][tid] = cy - ay;  sT[14][tid] = cz - az;
        }
        __syncthreads();

        for (int k = 0; k < 2; ++k) {
            int base = k * 128 + 2 * lane;           // even: 8B-aligned pair
            v2f ax  = *(const v2f*)&sT[0][base];
            v2f ay  = *(const v2f*)&sT[1][base];
            v2f az  = *(const v2f*)&sT[2][base];
            v2f bx  = *(const v2f*)&sT[3][base];
            v2f by  = *(const v2f*)&sT[4][base];
            v2f bz  = *(const v2f*)&sT[5][base];
            v2f cx  = *(const v2f*)&sT[6][base];
            v2f cy  = *(const v2f*)&sT[7][base];
            v2f cz  = *(const v2f*)&sT[8][base];
            v2f abx = *(const v2f*)&sT[9][base];
            v2f aby = *(const v2f*)&sT[10][base];
            v2f abz = *(const v2f*)&sT[11][base];
            v2f acx = *(const v2f*)&sT[12][base];
            v2f acy = *(const v2f*)&sT[13][base];
            v2f acz = *(const v2f*)&sT[14][base];

            v2f apx = px - ax, apy = py - ay, apz = pz - az;
            v2f d1 = (abx * apx + aby * apy) + abz * apz;
            v2f d2 = (acx * apx + acy * apy) + acz * apz;
            v2f bpx = px - bx, bpy = py - by, bpz = pz - bz;
            v2f d3 = (abx * bpx + aby * bpy) + abz * bpz;
            v2f d4 = (acx * bpx + acy * bpy) + acz * bpz;
            v2f cpx = px - cx, cpy = py - cy, cpz = pz - cz;
            v2f d5 = (abx * cpx + aby * cpy) + abz * cpz;
            v2f d6 = (acx * cpx + acy * cpy) + acz * cpz;

            v2f vc = d1 * d4 - d3 * d2;
            v2f vb = d5 * d2 - d1 * d6;
            v2f va = d3 * d6 - d5 * d4;
            v2f d43 = d4 - d3, d56 = d5 - d6;
            v2f g1 = d1 - d3;                 // t_ab denom (pre-fmax)
            v2f g2 = d2 - d6;                 // t_ac denom
            v2f g3 = d43 + d56;               // t_bc denom
            v2f g4 = (va + vb) + vc;          // interior denom

            float bu0, bv0, bw0, bu1, bv1, bw1;
            region_select(d1.x, d2.x, d3.x, d4.x, d5.x, d6.x,
                          va.x, vb.x, vc.x, d43.x, d56.x,
                          g1.x, g2.x, g3.x, g4.x, bu0, bv0, bw0);
            region_select(d1.y, d2.y, d3.y, d4.y, d5.y, d6.y,
                          va.y, vb.y, vc.y, d43.y, d56.y,
                          g1.y, g2.y, g3.y, g4.y, bu1, bv1, bw1);
            v2f bu = {bu0, bu1}, bv = {bv0, bv1}, bw = {bw0, bw1};

            // reference: cp = a*bu + b*bv + c*bw; dist2 = sum((p-cp)^2)
            v2f cpx2 = (ax * bu + bx * bv) + cx * bw;
            v2f cpy2 = (ay * bu + by * bv) + cy * bw;
            v2f cpz2 = (az * bu + bz * bv) + cz * bw;
            v2f dx = px - cpx2, dy = py - cpy2, dz = pz - cpz2;
            v2f dist2 = (dx * dx + dy * dy) + dz * dz;

            unsigned int b0 = __float_as_uint(dist2.x);   // even tri first
            if (b0 < best_bits) { best_bits = b0; best_idx = c * CHUNK + base; }
            unsigned int b1 = __float_as_uint(dist2.y);
            if (b1 < best_bits) { best_bits = b1; best_idx = c * CHUNK + base + 1; }
        }
    }

    // in-wave packed min: smallest (bits, idx) == first-match argmin
    unsigned long long key =
        ((unsigned long long)best_bits << 32) | (unsigned int)best_idx;
    #pragma unroll
    for (int off = 32; off > 0; off >>= 1) {
        unsigned int hi = (unsigned int)(key >> 32);
        unsigned int lo = (unsigned int)(key & 0xFFFFFFFFu);
        unsigned int ohi = __shfl_down(hi, off, 64);
        unsigned int olo = __shfl_down(lo, off, 64);
        unsigned long long ok = ((unsigned long long)ohi << 32) | olo;
        key = (ok < key) ? ok : key;
    }
    if (lane == 0) {
        out[1 + p]           = __uint_as_float((unsigned int)(key >> 32));
        out[1 + P_TOTAL + p] = (float)(unsigned int)(key & 0xFFFFFFFFu);
    }
}

// Deterministic single-block loss reduction: out[0] = sum(dist) * 1000/P.
// No atomics (R5: 8192 same-address atomicAdds cost +66us serialized tail).
__global__ __launch_bounds__(256) void msdf_loss(float* __restrict__ out)
{
    __shared__ float wsum[4];
    float s = 0.f;
    for (int k = 0; k < P_TOTAL / 256; ++k)
        s += out[1 + k * 256 + threadIdx.x];
    #pragma unroll
    for (int off = 32; off > 0; off >>= 1) s += __shfl_down(s, off, 64);
    int lane = threadIdx.x & 63, w = threadIdx.x >> 6;
    if (lane == 0) wsum[w] = s;
    __syncthreads();
    if (threadIdx.x == 0) {
        float tot = ((wsum[0] + wsum[1]) + wsum[2]) + wsum[3];
        out[0] = tot * (1000.0f / (float)P_TOTAL);
    }
}

extern "C" void kernel_launch(void* const* d_in, const int* in_sizes, int n_in,
                              void* d_out, int out_size, void* d_ws, size_t ws_size,
                              hipStream_t stream) {
    const float* verts  = (const float*)d_in[0];
    const int*   faces  = (const int*)d_in[1];
    const float* points = (const float*)d_in[2];
    float* out = (float*)d_out;

    msdf_main<<<dim3(P_TOTAL / 4), dim3(TPB), 0, stream>>>(verts, faces, points, out);
    msdf_loss<<<dim3(1), dim3(256), 0, stream>>>(out);
}

// Round 8
// 107.584 us; speedup vs baseline: 1.7291x; 1.0711x over previous
//
#include <hip/hip_runtime.h>

typedef float v2f __attribute__((ext_vector_type(2)));

#define P_TOTAL 8192
#define F_TOTAL 2048
#define TPB     256                      // 4 waves; wave w owns point base+w
#define CHUNK   256                      // tris staged per LDS pass
#define NCHUNK  (F_TOTAL / CHUNK)        // 8

// Correctly-rounded f32 division via shared refined reciprocal (Markstein).
// Valid here: D = fmax(.,1e-12) is normal, num finite, so the div_scale /
// div_fixup edge cases never apply. Tie partners present identical (num,D)
// bits -> identical q bits, preserving np's exact-tie structure.
__device__ __forceinline__ float refine_rcp(float D) {
#pragma clang fp contract(off)
    float r0 = __builtin_amdgcn_rcpf(D);
    float e1 = __builtin_fmaf(-D, r0, 1.0f);
    return __builtin_fmaf(e1, r0, r0);
}
__device__ __forceinline__ float div_rn(float num, float D, float r) {
#pragma clang fp contract(off)
    float q0 = num * r;
    float e  = __builtin_fmaf(-D, q0, num);
    return __builtin_fmaf(e, r, q0);
}

// Scalar region-select, bit-exact vs numpy (logic proven R2..R7): first-match
// region, then two divisions with reference-identical operands sharing one
// reciprocal of the common denominator D.
__device__ __forceinline__ void region_select(
    float d1, float d2, float d3, float d4, float d5, float d6,
    float va, float vb, float vc, float d43, float d56,
    float g1, float g2, float g3, float g4,
    float& bu, float& bv, float& bw)
{
#pragma clang fp contract(off)
    float G1 = fmaxf(g1, 1e-12f);          // t_ab denom
    float G2 = fmaxf(g2, 1e-12f);          // t_ac denom
    float G3 = fmaxf(g3, 1e-12f);          // t_bc denom
    float G4 = fmaxf(g4, 1e-12f);          // interior denom

    bool cA  = (d1 <= 0.f) & (d2 <= 0.f);
    bool cB  = (d3 >= 0.f) & (d4 <= d3);
    bool cAB = (vc <= 0.f) & (d1 >= 0.f) & (d3 <= 0.f);
    bool cC  = (d6 >= 0.f) & (d5 <= d6);
    bool cAC = (vb <= 0.f) & (d2 >= 0.f) & (d6 <= 0.f);
    bool cBC = (va <= 0.f) & (d43 >= 0.f) & (d56 >= 0.f);

    // first-match selects; shared denominator D is bit-safe (vertex regions
    // divide by 1.0; 0/G == +0 matches the reference's 0).
    float nv = cA ? 0.f : cB ? 1.f : cAB ? d1 : cC ? 0.f
             : cAC ? 0.f : cBC ? d43 : vb;
    float nw = cA ? 0.f : cB ? 0.f : cAB ? 0.f : cC ? 1.f
             : cAC ? d2 : cBC ? d43 : vc;
    float D  = cA ? 1.f : cB ? 1.f : cAB ? G1 : cC ? 1.f
             : cAC ? G2 : cBC ? G3 : G4;
    bool fBC = cBC && !(cA || cB || cAB || cC || cAC);

    float r   = refine_rcp(D);
    float qv  = div_rn(nv, D, r);          // == RN(nv/D), ref-identical operands
    float bww = div_rn(nw, D, r);
    float bvv = fBC ? (1.0f - qv) : qv;    // reference: 1.0 - t_bc
    bv = bvv; bw = bww;
    bu = (1.0f - bvv) - bww;
}

// Wave-per-point exact scan, 2 triangles/lane via packed f32 (VOP3P pk ops are
// element-wise IEEE -> bit-exact). LDS component-major float[9][256]: lane l
// reads tris (k*128+2l, +1) as aligned ds_read_b64 pairs. Edges ab/ac computed
// in-lane (same subtraction, same bits as staging them). Strict '<' in
// even-then-odd order preserves argmin first-match.
__global__ __launch_bounds__(TPB) void msdf_main(
    const float* __restrict__ verts, const int* __restrict__ faces,
    const float* __restrict__ points, float* __restrict__ out)
{
#pragma clang fp contract(off)
    __shared__ float sT[9][CHUNK];       // 9 KB, component-major
    const int tid  = threadIdx.x;
    const int lane = tid & 63;
    const int w    = tid >> 6;
    const int p    = blockIdx.x * 4 + w;          // wave-uniform point id

    const float px = points[3 * p], py = points[3 * p + 1], pz = points[3 * p + 2];

    unsigned int best_bits = 0xFFFFFFFFu;
    int best_idx = 0;

    for (int c = 0; c < NCHUNK; ++c) {
        __syncthreads();                 // protect LDS buffer reuse
        {   // stage: thread tid gathers tri c*256+tid; conflict-free writes
            int tg = c * CHUNK + tid;
            int i0 = faces[3 * tg + 0], i1 = faces[3 * tg + 1], i2 = faces[3 * tg + 2];
            sT[0][tid] = verts[3 * i0]; sT[1][tid] = verts[3 * i0 + 1]; sT[2][tid] = verts[3 * i0 + 2];
            sT[3][tid] = verts[3 * i1]; sT[4][tid] = verts[3 * i1 + 1]; sT[5][tid] = verts[3 * i1 + 2];
            sT[6][tid] = verts[3 * i2]; sT[7][tid] = verts[3 * i2 + 1]; sT[8][tid] = verts[3 * i2 + 2];
        }
        __syncthreads();

        #pragma unroll
        for (int k = 0; k < 2; ++k) {
            int base = k * 128 + 2 * lane;           // even: 8B-aligned pair
            v2f ax = *(const v2f*)&sT[0][base];
            v2f ay = *(const v2f*)&sT[1][base];
            v2f az = *(const v2f*)&sT[2][base];
            v2f bx = *(const v2f*)&sT[3][base];
            v2f by = *(const v2f*)&sT[4][base];
            v2f bz = *(const v2f*)&sT[5][base];
            v2f cx = *(const v2f*)&sT[6][base];
            v2f cy = *(const v2f*)&sT[7][base];
            v2f cz = *(const v2f*)&sT[8][base];

            v2f abx = bx - ax, aby = by - ay, abz = bz - az;   // same bits as
            v2f acx = cx - ax, acy = cy - ay, acz = cz - az;   // staged version

            v2f apx = px - ax, apy = py - ay, apz = pz - az;
            v2f d1 = (abx * apx + aby * apy) + abz * apz;
            v2f d2 = (acx * apx + acy * apy) + acz * apz;
            v2f bpx = px - bx, bpy = py - by, bpz = pz - bz;
            v2f d3 = (abx * bpx + aby * bpy) + abz * bpz;
            v2f d4 = (acx * bpx + acy * bpy) + acz * bpz;
            v2f cpx = px - cx, cpy = py - cy, cpz = pz - cz;
            v2f d5 = (abx * cpx + aby * cpy) + abz * cpz;
            v2f d6 = (acx * cpx + acy * cpy) + acz * cpz;

            v2f vc = d1 * d4 - d3 * d2;
            v2f vb = d5 * d2 - d1 * d6;
            v2f va = d3 * d6 - d5 * d4;
            v2f d43 = d4 - d3, d56 = d5 - d6;
            v2f g1 = d1 - d3;                 // t_ab denom (pre-fmax)
            v2f g2 = d2 - d6;                 // t_ac denom
            v2f g3 = d43 + d56;               // t_bc denom
            v2f g4 = (va + vb) + vc;          // interior denom

            float bu0, bv0, bw0, bu1, bv1, bw1;
            region_select(d1.x, d2.x, d3.x, d4.x, d5.x, d6.x,
                          va.x, vb.x, vc.x, d43.x, d56.x,
                          g1.x, g2.x, g3.x, g4.x, bu0, bv0, bw0);
            region_select(d1.y, d2.y, d3.y, d4.y, d5.y, d6.y,
                          va.y, vb.y, vc.y, d43.y, d56.y,
                          g1.y, g2.y, g3.y, g4.y, bu1, bv1, bw1);
            v2f bu = {bu0, bu1}, bv = {bv0, bv1}, bw = {bw0, bw1};

            // reference: cp = a*bu + b*bv + c*bw; dist2 = sum((p-cp)^2)
            v2f cpx2 = (ax * bu + bx * bv) + cx * bw;
            v2f cpy2 = (ay * bu + by * bv) + cy * bw;
            v2f cpz2 = (az * bu + bz * bv) + cz * bw;
            v2f dx = px - cpx2, dy = py - cpy2, dz = pz - cpz2;
            v2f dist2 = (dx * dx + dy * dy) + dz * dz;

            unsigned int b0 = __float_as_uint(dist2.x);   // even tri first
            if (b0 < best_bits) { best_bits = b0; best_idx = c * CHUNK + base; }
            unsigned int b1 = __float_as_uint(dist2.y);
            if (b1 < best_bits) { best_bits = b1; best_idx = c * CHUNK + base + 1; }
        }
    }

    // in-wave packed min: smallest (bits, idx) == first-match argmin
    unsigned long long key =
        ((unsigned long long)best_bits << 32) | (unsigned int)best_idx;
    #pragma unroll
    for (int off = 32; off > 0; off >>= 1) {
        unsigned int hi = (unsigned int)(key >> 32);
        unsigned int lo = (unsigned int)(key & 0xFFFFFFFFu);
        unsigned int ohi = __shfl_down(hi, off, 64);
        unsigned int olo = __shfl_down(lo, off, 64);
        unsigned long long ok = ((unsigned long long)ohi << 32) | olo;
        key = (ok < key) ? ok : key;
    }
    if (lane == 0) {
        out[1 + p]           = __uint_as_float((unsigned int)(key >> 32));
        out[1 + P_TOTAL + p] = (float)(unsigned int)(key & 0xFFFFFFFFu);
    }
}

// Deterministic single-block loss reduction: out[0] = sum(dist) * 1000/P.
// No atomics (R5: 8192 same-address atomicAdds cost +66us serialized tail).
__global__ __launch_bounds__(256) void msdf_loss(float* __restrict__ out)
{
    __shared__ float wsum[4];
    float s = 0.f;
    for (int k = 0; k < P_TOTAL / 256; ++k)
        s += out[1 + k * 256 + threadIdx.x];
    #pragma unroll
    for (int off = 32; off > 0; off >>= 1) s += __shfl_down(s, off, 64);
    int lane = threadIdx.x & 63, w = threadIdx.x >> 6;
    if (lane == 0) wsum[w] = s;
    __syncthreads();
    if (threadIdx.x == 0) {
        float tot = ((wsum[0] + wsum[1]) + wsum[2]) + wsum[3];
        out[0] = tot * (1000.0f / (float)P_TOTAL);
    }
}

extern "C" void kernel_launch(void* const* d_in, const int* in_sizes, int n_in,
                              void* d_out, int out_size, void* d_ws, size_t ws_size,
                              hipStream_t stream) {
    const float* verts  = (const float*)d_in[0];
    const int*   faces  = (const int*)d_in[1];
    const float* points = (const float*)d_in[2];
    float* out = (float*)d_out;

    msdf_main<<<dim3(P_TOTAL / 4), dim3(TPB), 0, stream>>>(verts, faces, points, out);
    msdf_loss<<<dim3(1), dim3(256), 0, stream>>>(out);
}

// Round 9
// 105.901 us; speedup vs baseline: 1.7566x; 1.0159x over previous
//
#include <hip/hip_runtime.h>

typedef float v2f __attribute__((ext_vector_type(2)));

#define P_TOTAL 8192
#define F_TOTAL 2048
#define TPB     256                      // 4 waves; wave w owns point base+w
#define CHUNK   256                      // tris staged per LDS pass
#define NCHUNK  (F_TOTAL / CHUNK)        // 8

// Correctly-rounded f32 division via shared refined reciprocal (Markstein).
// Valid here: D = fmax(.,1e-12) is normal, num finite. Tie partners present
// identical (num,D) bits -> identical q bits -> np's exact-tie structure kept.
__device__ __forceinline__ float refine_rcp(float D) {
#pragma clang fp contract(off)
    float r0 = __builtin_amdgcn_rcpf(D);
    float e1 = __builtin_fmaf(-D, r0, 1.0f);
    return __builtin_fmaf(e1, r0, r0);
}
__device__ __forceinline__ float div_rn(float num, float D, float r) {
#pragma clang fp contract(off)
    float q0 = num * r;
    float e  = __builtin_fmaf(-D, q0, num);
    return __builtin_fmaf(e, r, q0);
}

// Scalar region-select, bit-exact vs numpy (proven R2..R8): first-match
// region, then two divisions with reference-identical operands sharing one
// reciprocal of the common denominator D.
__device__ __forceinline__ void region_select(
    float d1, float d2, float d3, float d4, float d5, float d6,
    float va, float vb, float vc, float d43, float d56,
    float g1, float g2, float g3, float g4,
    float& bu, float& bv, float& bw)
{
#pragma clang fp contract(off)
    float G1 = fmaxf(g1, 1e-12f);          // t_ab denom
    float G2 = fmaxf(g2, 1e-12f);          // t_ac denom
    float G3 = fmaxf(g3, 1e-12f);          // t_bc denom
    float G4 = fmaxf(g4, 1e-12f);          // interior denom

    bool cA  = (d1 <= 0.f) & (d2 <= 0.f);
    bool cB  = (d3 >= 0.f) & (d4 <= d3);
    bool cAB = (vc <= 0.f) & (d1 >= 0.f) & (d3 <= 0.f);
    bool cC  = (d6 >= 0.f) & (d5 <= d6);
    bool cAC = (vb <= 0.f) & (d2 >= 0.f) & (d6 <= 0.f);
    bool cBC = (va <= 0.f) & (d43 >= 0.f) & (d56 >= 0.f);

    float nv = cA ? 0.f : cB ? 1.f : cAB ? d1 : cC ? 0.f
             : cAC ? 0.f : cBC ? d43 : vb;
    float nw = cA ? 0.f : cB ? 0.f : cAB ? 0.f : cC ? 1.f
             : cAC ? d2 : cBC ? d43 : vc;
    float D  = cA ? 1.f : cB ? 1.f : cAB ? G1 : cC ? 1.f
             : cAC ? G2 : cBC ? G3 : G4;
    bool fBC = cBC && !(cA || cB || cAB || cC || cAC);

    float r   = refine_rcp(D);
    float qv  = div_rn(nv, D, r);          // == RN(nv/D), ref-identical operands
    float bww = div_rn(nw, D, r);
    float bvv = fBC ? (1.0f - qv) : qv;    // reference: 1.0 - t_bc
    bv = bvv; bw = bww;
    bu = (1.0f - bvv) - bww;
}

// Wave-per-point exact scan, 2 tris/lane packed f32 (VOP3P, element-wise IEEE
// -> bit-exact). DOUBLE-BUFFERED LDS staging: next chunk's two-level gather
// (faces -> verts) is issued before computing the current chunk, written to
// the alternate buffer after, one barrier per chunk. Removes the ~500cyc
// gather latency that R8 exposed inside its 2-barriers-per-chunk structure
// (VALUBusy 69% -> idle was barrier-drain).
__global__ __launch_bounds__(TPB) void msdf_main(
    const float* __restrict__ verts, const int* __restrict__ faces,
    const float* __restrict__ points, float* __restrict__ out)
{
#pragma clang fp contract(off)
    __shared__ float sT[2][9][CHUNK];    // 18 KB, component-major, 2 buffers
    const int tid  = threadIdx.x;
    const int lane = tid & 63;
    const int w    = tid >> 6;
    const int p    = blockIdx.x * 4 + w;          // wave-uniform point id

    const float px = points[3 * p], py = points[3 * p + 1], pz = points[3 * p + 2];

    // prolog: stage chunk 0 into buffer 0
    {
        int tg = tid;
        int i0 = faces[3 * tg + 0], i1 = faces[3 * tg + 1], i2 = faces[3 * tg + 2];
        sT[0][0][tid] = verts[3 * i0]; sT[0][1][tid] = verts[3 * i0 + 1]; sT[0][2][tid] = verts[3 * i0 + 2];
        sT[0][3][tid] = verts[3 * i1]; sT[0][4][tid] = verts[3 * i1 + 1]; sT[0][5][tid] = verts[3 * i1 + 2];
        sT[0][6][tid] = verts[3 * i2]; sT[0][7][tid] = verts[3 * i2 + 1]; sT[0][8][tid] = verts[3 * i2 + 2];
    }
    __syncthreads();

    unsigned int best_bits = 0xFFFFFFFFu;
    int best_idx = 0;

    for (int c = 0; c < NCHUNK; ++c) {
        const int cur = c & 1;
        const bool have_next = (c + 1 < NCHUNK);

        // issue next chunk's gather early; latency hides under compute below
        float r0, r1, r2, r3, r4, r5, r6, r7, r8;
        if (have_next) {
            int tg = (c + 1) * CHUNK + tid;
            int i0 = faces[3 * tg + 0], i1 = faces[3 * tg + 1], i2 = faces[3 * tg + 2];
            r0 = verts[3 * i0]; r1 = verts[3 * i0 + 1]; r2 = verts[3 * i0 + 2];
            r3 = verts[3 * i1]; r4 = verts[3 * i1 + 1]; r5 = verts[3 * i1 + 2];
            r6 = verts[3 * i2]; r7 = verts[3 * i2 + 1]; r8 = verts[3 * i2 + 2];
        }

        #pragma unroll
        for (int k = 0; k < 2; ++k) {
            int base = k * 128 + 2 * lane;           // even: 8B-aligned pair
            v2f ax = *(const v2f*)&sT[cur][0][base];
            v2f ay = *(const v2f*)&sT[cur][1][base];
            v2f az = *(const v2f*)&sT[cur][2][base];
            v2f bx = *(const v2f*)&sT[cur][3][base];
            v2f by = *(const v2f*)&sT[cur][4][base];
            v2f bz = *(const v2f*)&sT[cur][5][base];
            v2f cx = *(const v2f*)&sT[cur][6][base];
            v2f cy = *(const v2f*)&sT[cur][7][base];
            v2f cz = *(const v2f*)&sT[cur][8][base];

            v2f abx = bx - ax, aby = by - ay, abz = bz - az;
            v2f acx = cx - ax, acy = cy - ay, acz = cz - az;

            v2f apx = px - ax, apy = py - ay, apz = pz - az;
            v2f d1 = (abx * apx + aby * apy) + abz * apz;
            v2f d2 = (acx * apx + acy * apy) + acz * apz;
            v2f bpx = px - bx, bpy = py - by, bpz = pz - bz;
            v2f d3 = (abx * bpx + aby * bpy) + abz * bpz;
            v2f d4 = (acx * bpx + acy * bpy) + acz * bpz;
            v2f cpx = px - cx, cpy = py - cy, cpz = pz - cz;
            v2f d5 = (abx * cpx + aby * cpy) + abz * cpz;
            v2f d6 = (acx * cpx + acy * cpy) + acz * cpz;

            v2f vc = d1 * d4 - d3 * d2;
            v2f vb = d5 * d2 - d1 * d6;
            v2f va = d3 * d6 - d5 * d4;
            v2f d43 = d4 - d3, d56 = d5 - d6;
            v2f g1 = d1 - d3;                 // t_ab denom (pre-fmax)
            v2f g2 = d2 - d6;                 // t_ac denom
            v2f g3 = d43 + d56;               // t_bc denom
            v2f g4 = (va + vb) + vc;          // interior denom

            float bu0, bv0, bw0, bu1, bv1, bw1;
            region_select(d1.x, d2.x, d3.x, d4.x, d5.x, d6.x,
                          va.x, vb.x, vc.x, d43.x, d56.x,
                          g1.x, g2.x, g3.x, g4.x, bu0, bv0, bw0);
            region_select(d1.y, d2.y, d3.y, d4.y, d5.y, d6.y,
                          va.y, vb.y, vc.y, d43.y, d56.y,
                          g1.y, g2.y, g3.y, g4.y, bu1, bv1, bw1);
            v2f bu = {bu0, bu1}, bv = {bv0, bv1}, bw = {bw0, bw1};

            // reference: cp = a*bu + b*bv + c*bw; dist2 = sum((p-cp)^2)
            v2f cpx2 = (ax * bu + bx * bv) + cx * bw;
            v2f cpy2 = (ay * bu + by * bv) + cy * bw;
            v2f cpz2 = (az * bu + bz * bv) + cz * bw;
            v2f dx = px - cpx2, dy = py - cpy2, dz = pz - cpz2;
            v2f dist2 = (dx * dx + dy * dy) + dz * dz;

            unsigned int b0 = __float_as_uint(dist2.x);   // even tri first
            if (b0 < best_bits) { best_bits = b0; best_idx = c * CHUNK + base; }
            unsigned int b1 = __float_as_uint(dist2.y);
            if (b1 < best_bits) { best_bits = b1; best_idx = c * CHUNK + base + 1; }
        }

        if (have_next) {
            int nxt = cur ^ 1;
            sT[nxt][0][tid] = r0; sT[nxt][1][tid] = r1; sT[nxt][2][tid] = r2;
            sT[nxt][3][tid] = r3; sT[nxt][4][tid] = r4; sT[nxt][5][tid] = r5;
            sT[nxt][6][tid] = r6; sT[nxt][7][tid] = r7; sT[nxt][8][tid] = r8;
        }
        __syncthreads();   // next buf written by all; cur buf free for reuse
    }

    // in-wave packed min: smallest (bits, idx) == first-match argmin
    unsigned long long key =
        ((unsigned long long)best_bits << 32) | (unsigned int)best_idx;
    #pragma unroll
    for (int off = 32; off > 0; off >>= 1) {
        unsigned int hi = (unsigned int)(key >> 32);
        unsigned int lo = (unsigned int)(key & 0xFFFFFFFFu);
        unsigned int ohi = __shfl_down(hi, off, 64);
        unsigned int olo = __shfl_down(lo, off, 64);
        unsigned long long ok = ((unsigned long long)ohi << 32) | olo;
        key = (ok < key) ? ok : key;
    }
    if (lane == 0) {
        out[1 + p]           = __uint_as_float((unsigned int)(key >> 32));
        out[1 + P_TOTAL + p] = (float)(unsigned int)(key & 0xFFFFFFFFu);
    }
}

// Deterministic single-block loss reduction: out[0] = sum(dist) * 1000/P.
// No atomics (R5: 8192 same-address atomicAdds cost +66us serialized tail).
__global__ __launch_bounds__(256) void msdf_loss(float* __restrict__ out)
{
    __shared__ float wsum[4];
    float s = 0.f;
    for (int k = 0; k < P_TOTAL / 256; ++k)
        s += out[1 + k * 256 + threadIdx.x];
    #pragma unroll
    for (int off = 32; off > 0; off >>= 1) s += __shfl_down(s, off, 64);
    int lane = threadIdx.x & 63, w = threadIdx.x >> 6;
    if (lane == 0) wsum[w] = s;
    __syncthreads();
    if (threadIdx.x == 0) {
        float tot = ((wsum[0] + wsum[1]) + wsum[2]) + wsum[3];
        out[0] = tot * (1000.0f / (float)P_TOTAL);
    }
}

extern "C" void kernel_launch(void* const* d_in, const int* in_sizes, int n_in,
                              void* d_out, int out_size, void* d_ws, size_t ws_size,
                              hipStream_t stream) {
    const float* verts  = (const float*)d_in[0];
    const int*   faces  = (const int*)d_in[1];
    const float* points = (const float*)d_in[2];
    float* out = (float*)d_out;

    msdf_main<<<dim3(P_TOTAL / 4), dim3(TPB), 0, stream>>>(verts, faces, points, out);
    msdf_loss<<<dim3(1), dim3(256), 0, stream>>>(out);
}